// Round 8
// baseline (111.436 us; speedup 1.0000x reference)
//
#include <hip/hip_runtime.h>
#include <math.h>

#define BB 4
#define LQ 2048
#define LK 2048
#define DK 512
#define DV 512

typedef __attribute__((ext_vector_type(8))) short bf16x8;
typedef __attribute__((ext_vector_type(4))) float f32x4;

// ws layout (f32-element offsets)
#define WS_QW    0                 // f32[8192]
#define WS_KW    8192              // f32[8192]
#define WS_M     16384             // f32[8192]
#define WS_INV   24576             // f32[8192]
#define WS_V16   557056            // u16 vH[4194304], u16 vL[4194304] = 16.8 MB
#define WS_PART  4751360           // f32[2*4194304] = 33.6 MB
#define WS_NEEDED_SPLIT ((size_t)(WS_PART + 2 * 4194304) * 4)

__device__ inline void bsplit(float f, unsigned short& h, unsigned short& l) {
    unsigned int u  = __float_as_uint(f);
    unsigned int hu = u & 0xFFFF0000u;
    float rest = f - __uint_as_float(hu);
    h = (unsigned short)(u >> 16);
    l = (unsigned short)(__float_as_uint(rest) >> 16);
}

__device__ inline unsigned int packsplit(float f) {
    unsigned int u  = __float_as_uint(f);
    unsigned int hu = u & 0xFFFF0000u;
    float rest = f - __uint_as_float(hu);
    return hu | (__float_as_uint(rest) >> 16);
}

// async global->LDS DMA, 16B per lane: lds dest = base + lane*16 (HW rule),
// global src = per-lane address (already lane-strided in our layouts).
__device__ __forceinline__ void dma16(const unsigned short* g, unsigned short* l) {
    __builtin_amdgcn_global_load_lds(
        (const __attribute__((address_space(1))) void*)g,
        (__attribute__((address_space(3))) void*)l,
        16, 0, 0);
}

// ---------------------------------------------------------------------------
// A: qw/kw — one wave per row.
// ---------------------------------------------------------------------------
__global__ __launch_bounds__(256) void qkw_kernel(const float* __restrict__ q,
                                                  const float* __restrict__ k,
                                                  const float* __restrict__ w,
                                                  float* __restrict__ ws) {
    int gw   = (int)((blockIdx.x * blockDim.x + threadIdx.x) >> 6);
    int lane = threadIdx.x & 63;
    const int nq = BB * LQ;
    const float* row = (gw < nq) ? (q + (size_t)gw * DK) : (k + (size_t)(gw - nq) * DK);

    float acc = 0.f;
#pragma unroll
    for (int j = 0; j < DK; j += 256) {
        int idx = j + lane * 4;
        float4 rv = *reinterpret_cast<const float4*>(row + idx);
        float4 wv = *reinterpret_cast<const float4*>(w + idx);
        acc += rv.x * wv.x + rv.y * wv.y + rv.z * wv.z + rv.w * wv.w;
    }
#pragma unroll
    for (int off = 32; off >= 1; off >>= 1) acc += __shfl_xor(acc, off, 64);
    if (lane == 0) ws[gw] = acc;
}

// ---------------------------------------------------------------------------
// C: v -> MFMA-fragment-ordered split bf16 (hi/lo).
// vFrag u16 index: (((b*32 + n16)*64 + k32)*64 + lane)*8 + j
//   element = vT[n16*16 + (lane&15)][k32*32 + (lane>>4)*8 + j]
// ---------------------------------------------------------------------------
__global__ __launch_bounds__(256) void vpack_kernel(const float* __restrict__ v,
                                                    unsigned short* __restrict__ vH,
                                                    unsigned short* __restrict__ vL) {
    __shared__ unsigned int tile[32][517];
    const int k32 = blockIdx.x;
    const int b   = blockIdx.y;
    const int k0  = k32 * 32;
    const int t   = threadIdx.x;

#pragma unroll
    for (int i = 0; i < 16; ++i) {
        int flat = i * 256 + t;          // 0..4095
        int row  = flat >> 7;            // 0..31
        int c4   = flat & 127;           // float4 col
        float4 f = *reinterpret_cast<const float4*>(
            v + ((size_t)(b * LK + k0 + row)) * DV + c4 * 4);
        tile[row][c4 * 4 + 0] = packsplit(f.x);
        tile[row][c4 * 4 + 1] = packsplit(f.y);
        tile[row][c4 * 4 + 2] = packsplit(f.z);
        tile[row][c4 * 4 + 3] = packsplit(f.w);
    }
    __syncthreads();

    const int w = t >> 6, l = t & 63;
    const int rbase = (l >> 4) * 8;
#pragma unroll
    for (int f = 0; f < 8; ++f) {
        int n16 = w * 8 + f;
        int col = n16 * 16 + (l & 15);
        unsigned int pk[8];
#pragma unroll
        for (int j = 0; j < 8; ++j) pk[j] = tile[rbase + j][col];
        uint4 hiw, low;
        hiw.x = (pk[0] >> 16) | (pk[1] & 0xFFFF0000u);
        hiw.y = (pk[2] >> 16) | (pk[3] & 0xFFFF0000u);
        hiw.z = (pk[4] >> 16) | (pk[5] & 0xFFFF0000u);
        hiw.w = (pk[6] >> 16) | (pk[7] & 0xFFFF0000u);
        low.x = (pk[0] & 0xFFFFu) | (pk[1] << 16);
        low.y = (pk[2] & 0xFFFFu) | (pk[3] << 16);
        low.z = (pk[4] & 0xFFFFu) | (pk[5] << 16);
        low.w = (pk[6] & 0xFFFFu) | (pk[7] << 16);
        size_t u16base = (((size_t)(b * 32 + n16)) * 64 + k32) * 512;
        *reinterpret_cast<uint4*>(vH + u16base + l * 8) = hiw;
        *reinterpret_cast<uint4*>(vL + u16base + l * 8) = low;
    }
}

// ---------------------------------------------------------------------------
// B1: per-row masked softmax stats + full attn row write.
// ---------------------------------------------------------------------------
__global__ __launch_bounds__(256) void rowstat_kernel(const int* __restrict__ mask,
                                                      float* __restrict__ ws,
                                                      float* __restrict__ attn) {
    __shared__ float kws[LK];
    const int b = (blockIdx.x * 4) / LQ;
    const int t = threadIdx.x;

    const float4* kw4 = reinterpret_cast<const float4*>(ws + WS_KW + b * LK);
#pragma unroll
    for (int i = 0; i < 2; ++i)
        reinterpret_cast<float4*>(kws)[t + i * 256] = kw4[t + i * 256];
    __syncthreads();

    const int wave = t >> 6, lane = t & 63;
    const int rid  = blockIdx.x * 4 + wave;
    const float qwv = ws[WS_QW + rid];
    const int* mrow = mask + (size_t)rid * LK;

    float m = -INFINITY, s = 0.f;
    unsigned int mybits = 0;   // nibble i = mask bits for k = (i*64+lane)*4 ..+3
#pragma unroll
    for (int i = 0; i < 8; ++i) {
        int e = (i * 64 + lane) * 4;
        int4  mi = *reinterpret_cast<const int4*>(mrow + e);
        float4 kv = reinterpret_cast<const float4*>(kws)[i * 64 + lane];
        float vals[4] = {kv.x, kv.y, kv.z, kv.w};
        int   msks[4] = {mi.x, mi.y, mi.z, mi.w};

        unsigned int bits = (msks[0] ? 1u : 0u) | (msks[1] ? 2u : 0u) |
                            (msks[2] ? 4u : 0u) | (msks[3] ? 8u : 0u);
        mybits |= bits << (i * 4);

#pragma unroll
        for (int j = 0; j < 4; ++j) {
            float sc = qwv - vals[j];
            sc = fmaxf(sc, 0.01f * sc);
            if (msks[j]) {
                if (sc > m) { s = s * __expf(m - sc) + 1.f; m = sc; }
                else        { s += __expf(sc - m); }
            }
        }
    }
#pragma unroll
    for (int off = 32; off >= 1; off >>= 1) {
        float mo = __shfl_xor(m, off, 64);
        float so = __shfl_xor(s, off, 64);
        float M  = fmaxf(m, mo);
        float sa = (m  == M) ? s  : s  * __expf(m  - M);
        float sb = (mo == M) ? so : so * __expf(mo - M);
        m = M; s = sa + sb;
    }
    const float inv = (s > 0.f) ? 1.f / s : 0.f;
    if (lane == 0) {
        ws[WS_M   + rid] = m;
        ws[WS_INV + rid] = inv;
    }

    // ---- pass 2: exact p, coalesced attn write ----
    float* arow = attn + (size_t)rid * LK;
#pragma unroll
    for (int i = 0; i < 8; ++i) {
        float4 kv = reinterpret_cast<const float4*>(kws)[i * 64 + lane];
        float vals[4] = {kv.x, kv.y, kv.z, kv.w};
        unsigned int bits = (mybits >> (i * 4)) & 0xFu;
        float p[4];
#pragma unroll
        for (int j = 0; j < 4; ++j) {
            float sc = qwv - vals[j];
            sc = fmaxf(sc, 0.01f * sc);
            p[j] = (bits & (1u << j)) ? __expf(sc - m) * inv : 0.f;
        }
        *reinterpret_cast<float4*>(arow + (i * 64 + lane) * 4) =
            make_float4(p[0], p[1], p[2], p[3]);
    }
}

// ---------------------------------------------------------------------------
// B2: PV matmul. A: attn f32 -> bsplit -> dbuf LDS (as R7).
// B: global_load_lds DMA into 64KB dbuf LDS (no VGPR prefetch, no vmcnt in
// MFMA stream; DMA drains at the end-of-step barrier under the MFMA shadow).
// M=64 q-tile, 512 thr (8 waves), wave = 64 q-rows x 64 n-cols. 1 barrier/step.
// ---------------------------------------------------------------------------
__global__ __launch_bounds__(512, 2) void pv_kernel(
        const float* __restrict__ attn,
        const unsigned short* __restrict__ vH,
        const unsigned short* __restrict__ vL,
        float* __restrict__ dst,
        int nks) {
    __shared__ unsigned int pH32[2][1024];            // 8 KB
    __shared__ unsigned int pL32[2][1024];            // 8 KB
    __shared__ unsigned short Bl[2][8][8][512];       // 128 KB: [buf][wave][chunk][1KB]

    const int bid = blockIdx.x;
    const int ks  = (nks == 2) ? (bid & 1) : 0;
    const int rst = (nks == 2) ? (bid >> 1) : bid;
    const int b   = rst & 3;
    const int qt  = rst >> 2;              // 0..31
    const int kspan  = LK / nks;
    const int ksteps = kspan >> 5;
    const int kbase  = ks * kspan;
    float* dstk = dst + (size_t)ks * ((size_t)BB * LQ * DV);

    const int t = threadIdx.x;
    const int w = t >> 6, l = t & 63;

    // staging decode: thread t owns LDS u32 words t (rows 0..31) and t+512 (32..63)
    const int m0   = t >> 8;               // 0..1
    const int lp   = (t >> 2) & 63;
    const int jp   = t & 3;
    const int row0 = m0 * 16 + (lp & 15);  // 0..31
    const int kk   = ((lp >> 4) << 3) + (jp << 1);   // even, 0..30
    const int rid0 = b * LQ + qt * 64 + row0;
    const int rid1 = rid0 + 32;

    const float* arow0 = attn + (size_t)rid0 * LK + kbase + kk;
    const float* arow1 = attn + (size_t)rid1 * LK + kbase + kk;

    // B fragment base pointers (u16 units), chunk 0, per nb; lane offset included
    const unsigned short* bsrc[8];
#pragma unroll
    for (int nb = 0; nb < 4; ++nb) {
        size_t off = (((size_t)(b * 32 + w * 4 + nb)) * 64 + (kbase >> 5)) * 512 + (size_t)l * 8;
        bsrc[nb * 2]     = vH + off;
        bsrc[nb * 2 + 1] = vL + off;
    }

    // prologue: DMA B(0) into buf0; stage A(0) into buf0; A(1) in regs
#pragma unroll
    for (int ch = 0; ch < 8; ++ch)
        dma16(bsrc[ch], &Bl[0][w][ch][0]);

    {
        float2 a00 = *reinterpret_cast<const float2*>(arow0);
        float2 a01 = *reinterpret_cast<const float2*>(arow1);
        unsigned short h0, lo0, h1, lo1;
        bsplit(a00.x, h0, lo0); bsplit(a00.y, h1, lo1);
        pH32[0][t] = (unsigned int)h0 | ((unsigned int)h1 << 16);
        pL32[0][t] = (unsigned int)lo0 | ((unsigned int)lo1 << 16);
        bsplit(a01.x, h0, lo0); bsplit(a01.y, h1, lo1);
        pH32[0][t + 512] = (unsigned int)h0 | ((unsigned int)h1 << 16);
        pL32[0][t + 512] = (unsigned int)lo0 | ((unsigned int)lo1 << 16);
    }
    const int s1 = (ksteps > 1) ? 1 : 0;
    float2 aC0 = *reinterpret_cast<const float2*>(arow0 + s1 * 32);
    float2 aC1 = *reinterpret_cast<const float2*>(arow1 + s1 * 32);

    f32x4 acc[4][4];
#pragma unroll
    for (int mf = 0; mf < 4; ++mf)
#pragma unroll
        for (int nb = 0; nb < 4; ++nb)
            acc[mf][nb] = (f32x4){0.f, 0.f, 0.f, 0.f};

    __syncthreads();   // drains prologue DMA + loads

    for (int s = 0; s < ksteps; ++s) {
        const int buf  = s & 1;
        const int nbuf = buf ^ 1;
        const int sn   = (s + 1 < ksteps) ? s + 1 : s;   // B DMA target step
        const int sn2  = (s + 2 < ksteps) ? s + 2 : s;   // A prefetch step

        // 1. DMA B(s+1) into Bl[nbuf] (async; drains at this step's barrier)
#pragma unroll
        for (int ch = 0; ch < 8; ++ch)
            dma16(bsrc[ch] + (size_t)sn * 512, &Bl[nbuf][w][ch][0]);

        // 2. A global prefetch (s+2)
        float2 aN0 = *reinterpret_cast<const float2*>(arow0 + sn2 * 32);
        float2 aN1 = *reinterpret_cast<const float2*>(arow1 + sn2 * 32);

        // 3. stage A(s+1) (regs) into pH/pL[nbuf] — pure VALU + ds_write
        {
            unsigned short h0, lo0, h1, lo1;
            bsplit(aC0.x, h0, lo0); bsplit(aC0.y, h1, lo1);
            pH32[nbuf][t] = (unsigned int)h0 | ((unsigned int)h1 << 16);
            pL32[nbuf][t] = (unsigned int)lo0 | ((unsigned int)lo1 << 16);
            bsplit(aC1.x, h0, lo0); bsplit(aC1.y, h1, lo1);
            pH32[nbuf][t + 512] = (unsigned int)h0 | ((unsigned int)h1 << 16);
            pL32[nbuf][t + 512] = (unsigned int)lo0 | ((unsigned int)lo1 << 16);
        }

        // 4. ds_read this step's A and B fragments from [buf]
        const bf16x8* pHf = reinterpret_cast<const bf16x8*>(pH32[buf]);
        const bf16x8* pLf = reinterpret_cast<const bf16x8*>(pL32[buf]);
        bf16x8 aH[4], aL[4];
#pragma unroll
        for (int mf = 0; mf < 4; ++mf) {
            aH[mf] = pHf[mf * 64 + l];
            aL[mf] = pLf[mf * 64 + l];
        }
        bf16x8 bh[4], blv[4];
#pragma unroll
        for (int nb = 0; nb < 4; ++nb) {
            bh[nb]  = *reinterpret_cast<const bf16x8*>(&Bl[buf][w][nb * 2][l * 8]);
            blv[nb] = *reinterpret_cast<const bf16x8*>(&Bl[buf][w][nb * 2 + 1][l * 8]);
        }

        // 5. MFMA cluster
        __builtin_amdgcn_s_setprio(1);
#pragma unroll
        for (int nb = 0; nb < 4; ++nb)
#pragma unroll
            for (int mf = 0; mf < 4; ++mf) {
                acc[mf][nb] = __builtin_amdgcn_mfma_f32_16x16x32_bf16(aH[mf], bh[nb],  acc[mf][nb], 0, 0, 0);
                acc[mf][nb] = __builtin_amdgcn_mfma_f32_16x16x32_bf16(aH[mf], blv[nb], acc[mf][nb], 0, 0, 0);
                acc[mf][nb] = __builtin_amdgcn_mfma_f32_16x16x32_bf16(aL[mf], bh[nb],  acc[mf][nb], 0, 0, 0);
            }
        __builtin_amdgcn_s_setprio(0);

        __syncthreads();   // single barrier: drains DMA(s+1), A(s+2) loads, LDS ops

        aC0 = aN0; aC1 = aN1;
    }

    // ---- epilogue: C layout col = l&15, row = mf*16 + (l>>4)*4 + r ----
    float* obase = dstk + ((size_t)(b * LQ + qt * 64)) * DV + w * 64 + (l & 15);
#pragma unroll
    for (int mf = 0; mf < 4; ++mf)
#pragma unroll
        for (int nb = 0; nb < 4; ++nb)
#pragma unroll
            for (int r = 0; r < 4; ++r)
                obase[(size_t)(mf * 16 + (l >> 4) * 4 + r) * DV + nb * 16] = acc[mf][nb][r];
}

// ---------------------------------------------------------------------------
// Reduce: out = part0 + part1 (float4).
// ---------------------------------------------------------------------------
__global__ __launch_bounds__(256) void reduce_kernel(const float* __restrict__ p0,
                                                     const float* __restrict__ p1,
                                                     float* __restrict__ out) {
    const int n4 = BB * LQ * DV / 4;   // 1048576
    int i = blockIdx.x * 256 + threadIdx.x;
    const float4* a = reinterpret_cast<const float4*>(p0);
    const float4* c = reinterpret_cast<const float4*>(p1);
    float4* o = reinterpret_cast<float4*>(out);
    for (; i < n4; i += 262144) {
        float4 x = a[i], y = c[i];
        o[i] = make_float4(x.x + y.x, x.y + y.y, x.z + y.z, x.w + y.w);
    }
}

// ---------------------------------------------------------------------------
extern "C" void kernel_launch(void* const* d_in, const int* in_sizes, int n_in,
                              void* d_out, int out_size, void* d_ws, size_t ws_size,
                              hipStream_t stream) {
    const float* q    = (const float*)d_in[0];
    const float* k    = (const float*)d_in[1];
    const float* v    = (const float*)d_in[2];
    const int*   mask = (const int*)d_in[3];
    const float* w    = (const float*)d_in[4];

    float* out  = (float*)d_out;                       // [B, LQ, DV]
    float* attn = out + (size_t)BB * LQ * DV;          // [B, LQ, LK]
    float* ws   = (float*)d_ws;

    unsigned short* vH    = (unsigned short*)(ws + WS_V16);
    unsigned short* vL    = vH + (size_t)BB * DV * LK;
    float* part0 = ws + WS_PART;
    float* part1 = part0 + (size_t)BB * LQ * DV;

    const bool split = ws_size >= WS_NEEDED_SPLIT;

    qkw_kernel<<<4096, 256, 0, stream>>>(q, k, w, ws);
    vpack_kernel<<<dim3(64, 4), 256, 0, stream>>>(v, vH, vL);
    rowstat_kernel<<<2048, 256, 0, stream>>>(mask, ws, attn);

    if (split) {
        // bid&7 = (ks, b) -> one (batch, k-half) v-slice per XCD (L2 locality)
        pv_kernel<<<256, 512, 0, stream>>>(attn, vH, vL, part0, 2);
        reduce_kernel<<<1024, 256, 0, stream>>>(part0, part1, out);
    } else {
        pv_kernel<<<128, 512, 0, stream>>>(attn, vH, vL, out, 1);
    }
}

// Round 10
// 93.286 us; speedup vs baseline: 1.1946x; 1.1946x over previous
//
#include <hip/hip_runtime.h>
#include <math.h>

#define BB 4
#define LQ 2048
#define LK 2048
#define DK 512
#define DV 512

typedef __attribute__((ext_vector_type(8))) _Float16 f16x8;
typedef __attribute__((ext_vector_type(2))) _Float16 f16x2;
typedef __attribute__((ext_vector_type(4))) float f32x4;

// ws layout (f32-element offsets)
#define WS_QW    0                 // f32[8192]
#define WS_KW    8192              // f32[8192]
#define WS_M     16384             // f32[8192]
#define WS_INV   24576             // f32[8192]
#define WS_VF16  32768             // u16 vF[4,194,304] = 8.4 MB (2,097,152 f32 slots)
#define WS_PART  2129920           // f32[nks * 4,194,304]
#define NOUT     ((size_t)BB * LQ * DV)
#define WS_NEED(nks) (((size_t)WS_PART + (size_t)(nks) * NOUT) * 4)

__device__ __forceinline__ unsigned int pk2(float a, float b) {
    auto h = __builtin_amdgcn_cvt_pkrtz(a, b);   // __fp16 ext_vector(2)
    return __builtin_bit_cast(unsigned int, h);
}

// ---------------------------------------------------------------------------
// A: qw/kw — one wave per row.
// ---------------------------------------------------------------------------
__global__ __launch_bounds__(256) void qkw_kernel(const float* __restrict__ q,
                                                  const float* __restrict__ k,
                                                  const float* __restrict__ w,
                                                  float* __restrict__ ws) {
    int gw   = (int)((blockIdx.x * blockDim.x + threadIdx.x) >> 6);
    int lane = threadIdx.x & 63;
    const int nq = BB * LQ;
    const float* row = (gw < nq) ? (q + (size_t)gw * DK) : (k + (size_t)(gw - nq) * DK);

    float acc = 0.f;
#pragma unroll
    for (int j = 0; j < DK; j += 256) {
        int idx = j + lane * 4;
        float4 rv = *reinterpret_cast<const float4*>(row + idx);
        float4 wv = *reinterpret_cast<const float4*>(w + idx);
        acc += rv.x * wv.x + rv.y * wv.y + rv.z * wv.z + rv.w * wv.w;
    }
#pragma unroll
    for (int off = 32; off >= 1; off >>= 1) acc += __shfl_xor(acc, off, 64);
    if (lane == 0) ws[gw] = acc;
}

// ---------------------------------------------------------------------------
// C: v -> MFMA-fragment-ordered fp16 (RTN).
// vF u16 index: (((b*32 + n16)*64 + k32)*64 + lane)*8 + j
//   element = vT[n16*16 + (lane&15)][k32*32 + (lane>>4)*8 + j]
// ---------------------------------------------------------------------------
__global__ __launch_bounds__(256) void vpack_kernel(const float* __restrict__ v,
                                                    unsigned short* __restrict__ vF) {
    __shared__ float tile[32][517];
    const int k32 = blockIdx.x;
    const int b   = blockIdx.y;
    const int k0  = k32 * 32;
    const int t   = threadIdx.x;

#pragma unroll
    for (int i = 0; i < 16; ++i) {
        int flat = i * 256 + t;          // 0..4095
        int row  = flat >> 7;            // 0..31
        int c4   = flat & 127;           // float4 col
        float4 f = *reinterpret_cast<const float4*>(
            v + ((size_t)(b * LK + k0 + row)) * DV + c4 * 4);
        tile[row][c4 * 4 + 0] = f.x;
        tile[row][c4 * 4 + 1] = f.y;
        tile[row][c4 * 4 + 2] = f.z;
        tile[row][c4 * 4 + 3] = f.w;
    }
    __syncthreads();

    const int w = t >> 6, l = t & 63;
    const int rbase = (l >> 4) * 8;
#pragma unroll
    for (int f = 0; f < 8; ++f) {
        int n16 = w * 8 + f;
        int col = n16 * 16 + (l & 15);
        f16x8 vv;
#pragma unroll
        for (int j = 0; j < 8; ++j) vv[j] = (_Float16)tile[rbase + j][col];
        size_t u16base = (((size_t)(b * 32 + n16)) * 64 + k32) * 512;
        *reinterpret_cast<f16x8*>(vF + u16base + l * 8) = vv;
    }
}

// ---------------------------------------------------------------------------
// B1: per-row masked softmax stats + full attn row write.
// ---------------------------------------------------------------------------
__global__ __launch_bounds__(256) void rowstat_kernel(const int* __restrict__ mask,
                                                      float* __restrict__ ws,
                                                      float* __restrict__ attn) {
    __shared__ float kws[LK];
    const int b = (blockIdx.x * 4) / LQ;
    const int t = threadIdx.x;

    const float4* kw4 = reinterpret_cast<const float4*>(ws + WS_KW + b * LK);
#pragma unroll
    for (int i = 0; i < 2; ++i)
        reinterpret_cast<float4*>(kws)[t + i * 256] = kw4[t + i * 256];
    __syncthreads();

    const int wave = t >> 6, lane = t & 63;
    const int rid  = blockIdx.x * 4 + wave;
    const float qwv = ws[WS_QW + rid];
    const int* mrow = mask + (size_t)rid * LK;

    float m = -INFINITY, s = 0.f;
    unsigned int mybits = 0;   // nibble i = mask bits for k = (i*64+lane)*4 ..+3
#pragma unroll
    for (int i = 0; i < 8; ++i) {
        int e = (i * 64 + lane) * 4;
        int4  mi = *reinterpret_cast<const int4*>(mrow + e);
        float4 kv = reinterpret_cast<const float4*>(kws)[i * 64 + lane];
        float vals[4] = {kv.x, kv.y, kv.z, kv.w};
        int   msks[4] = {mi.x, mi.y, mi.z, mi.w};

        unsigned int bits = (msks[0] ? 1u : 0u) | (msks[1] ? 2u : 0u) |
                            (msks[2] ? 4u : 0u) | (msks[3] ? 8u : 0u);
        mybits |= bits << (i * 4);

#pragma unroll
        for (int j = 0; j < 4; ++j) {
            float sc = qwv - vals[j];
            sc = fmaxf(sc, 0.01f * sc);
            if (msks[j]) {
                if (sc > m) { s = s * __expf(m - sc) + 1.f; m = sc; }
                else        { s += __expf(sc - m); }
            }
        }
    }
#pragma unroll
    for (int off = 32; off >= 1; off >>= 1) {
        float mo = __shfl_xor(m, off, 64);
        float so = __shfl_xor(s, off, 64);
        float M  = fmaxf(m, mo);
        float sa = (m  == M) ? s  : s  * __expf(m  - M);
        float sb = (mo == M) ? so : so * __expf(mo - M);
        m = M; s = sa + sb;
    }
    const float inv = (s > 0.f) ? 1.f / s : 0.f;
    if (lane == 0) {
        ws[WS_M   + rid] = m;
        ws[WS_INV + rid] = inv;
    }

    // ---- pass 2: exact p, coalesced attn write ----
    float* arow = attn + (size_t)rid * LK;
#pragma unroll
    for (int i = 0; i < 8; ++i) {
        float4 kv = reinterpret_cast<const float4*>(kws)[i * 64 + lane];
        float vals[4] = {kv.x, kv.y, kv.z, kv.w};
        unsigned int bits = (mybits >> (i * 4)) & 0xFu;
        float p[4];
#pragma unroll
        for (int j = 0; j < 4; ++j) {
            float sc = qwv - vals[j];
            sc = fmaxf(sc, 0.01f * sc);
            p[j] = (bits & (1u << j)) ? __expf(sc - m) * inv : 0.f;
        }
        *reinterpret_cast<float4*>(arow + (i * 64 + lane) * 4) =
            make_float4(p[0], p[1], p[2], p[3]);
    }
}

// ---------------------------------------------------------------------------
// B2: PV matmul, fp16 two-term (p = h16 + r16; v = v16 RTN).
// A: attn f32 -> cvt_pkrtz -> dbuf LDS. B: global b128 loads (L2-resident vF).
// M=64 q-tile, 512 thr (8 waves), wave = 64 q-rows x 64 n-cols. 1 barrier/step.
// K split nks ways -> 2 blocks/CU at nks=4 (overhead overlap across blocks).
// ---------------------------------------------------------------------------
__global__ __launch_bounds__(512, 2) void pv_kernel(
        const float* __restrict__ attn,
        const unsigned short* __restrict__ vF,
        float* __restrict__ dst,
        int nks) {
    __shared__ unsigned int pH32[2][1024];   // hi fp16 pairs
    __shared__ unsigned int pL32[2][1024];   // residual fp16 pairs

    const int bid = blockIdx.x;
    const int ks  = bid & (nks - 1);
    const int rst = bid / nks;
    const int b   = rst & 3;
    const int qt  = rst >> 2;              // 0..31
    const int kspan  = LK / nks;
    const int ksteps = kspan >> 5;
    const int kbase  = ks * kspan;
    float* dstk = dst + (size_t)ks * NOUT;

    const int t = threadIdx.x;
    const int w = t >> 6, l = t & 63;

    // staging decode: thread t owns LDS u32 words t (rows 0..31) and t+512 (32..63)
    const int m0   = t >> 8;               // 0..1
    const int lp   = (t >> 2) & 63;
    const int jp   = t & 3;
    const int row0 = m0 * 16 + (lp & 15);  // 0..31
    const int kk   = ((lp >> 4) << 3) + (jp << 1);   // even, 0..30
    const int rid0 = b * LQ + qt * 64 + row0;
    const int rid1 = rid0 + 32;

    const float* arow0 = attn + (size_t)rid0 * LK + kbase + kk;
    const float* arow1 = attn + (size_t)rid1 * LK + kbase + kk;

    // B fragment base pointers (u16 units), chunk 0, per nb; lane offset included
    const unsigned short* bsrc[4];
#pragma unroll
    for (int nb = 0; nb < 4; ++nb)
        bsrc[nb] = vF + (((size_t)(b * 32 + w * 4 + nb)) * 64 + (kbase >> 5)) * 512
                      + (size_t)l * 8;

    // prologue: B(0) into regs; A(0) staged to buf0; A(1) in regs
    f16x8 bC[4], bN[4];
#pragma unroll
    for (int nb = 0; nb < 4; ++nb)
        bC[nb] = *reinterpret_cast<const f16x8*>(bsrc[nb]);

    {
        float2 a00 = *reinterpret_cast<const float2*>(arow0);
        float2 a01 = *reinterpret_cast<const float2*>(arow1);
        unsigned int h01 = pk2(a00.x, a00.y);
        f16x2 hv = __builtin_bit_cast(f16x2, h01);
        pH32[0][t] = h01;
        pL32[0][t] = pk2(a00.x - (float)hv[0], a00.y - (float)hv[1]);
        h01 = pk2(a01.x, a01.y);
        hv  = __builtin_bit_cast(f16x2, h01);
        pH32[0][t + 512] = h01;
        pL32[0][t + 512] = pk2(a01.x - (float)hv[0], a01.y - (float)hv[1]);
    }
    const int s1 = (ksteps > 1) ? 1 : 0;
    float2 aC0 = *reinterpret_cast<const float2*>(arow0 + s1 * 32);
    float2 aC1 = *reinterpret_cast<const float2*>(arow1 + s1 * 32);

    f32x4 acc[4][4];
#pragma unroll
    for (int mf = 0; mf < 4; ++mf)
#pragma unroll
        for (int nb = 0; nb < 4; ++nb)
            acc[mf][nb] = (f32x4){0.f, 0.f, 0.f, 0.f};

    __syncthreads();

    for (int s = 0; s < ksteps; ++s) {
        const int buf  = s & 1;
        const int nbuf = buf ^ 1;
        const int sn   = (s + 1 < ksteps) ? s + 1 : s;   // B prefetch step
        const int sn2  = (s + 2 < ksteps) ? s + 2 : s;   // A prefetch step

        // 1. global prefetches
#pragma unroll
        for (int nb = 0; nb < 4; ++nb)
            bN[nb] = *reinterpret_cast<const f16x8*>(bsrc[nb] + (size_t)sn * 512);
        float2 aN0 = *reinterpret_cast<const float2*>(arow0 + sn2 * 32);
        float2 aN1 = *reinterpret_cast<const float2*>(arow1 + sn2 * 32);

        // 2. stage A(s+1) (regs from last iter) into nbuf
        {
            unsigned int h01 = pk2(aC0.x, aC0.y);
            f16x2 hv = __builtin_bit_cast(f16x2, h01);
            pH32[nbuf][t] = h01;
            pL32[nbuf][t] = pk2(aC0.x - (float)hv[0], aC0.y - (float)hv[1]);
            h01 = pk2(aC1.x, aC1.y);
            hv  = __builtin_bit_cast(f16x2, h01);
            pH32[nbuf][t + 512] = h01;
            pL32[nbuf][t + 512] = pk2(aC1.x - (float)hv[0], aC1.y - (float)hv[1]);
        }

        // 3. ds_read this step's A fragments from buf
        const f16x8* pHf = reinterpret_cast<const f16x8*>(pH32[buf]);
        const f16x8* pLf = reinterpret_cast<const f16x8*>(pL32[buf]);
        f16x8 aH[4], aL[4];
#pragma unroll
        for (int mf = 0; mf < 4; ++mf) {
            aH[mf] = pHf[mf * 64 + l];
            aL[mf] = pLf[mf * 64 + l];
        }

        // 4. MFMA cluster (2 per mf,nb)
        __builtin_amdgcn_s_setprio(1);
#pragma unroll
        for (int nb = 0; nb < 4; ++nb)
#pragma unroll
            for (int mf = 0; mf < 4; ++mf) {
                acc[mf][nb] = __builtin_amdgcn_mfma_f32_16x16x32_f16(aH[mf], bC[nb], acc[mf][nb], 0, 0, 0);
                acc[mf][nb] = __builtin_amdgcn_mfma_f32_16x16x32_f16(aL[mf], bC[nb], acc[mf][nb], 0, 0, 0);
            }
        __builtin_amdgcn_s_setprio(0);

        __syncthreads();   // single barrier per step

#pragma unroll
        for (int nb = 0; nb < 4; ++nb) bC[nb] = bN[nb];
        aC0 = aN0; aC1 = aN1;
    }

    // ---- epilogue: C layout col = l&15, row = mf*16 + (l>>4)*4 + r ----
    float* obase = dstk + ((size_t)(b * LQ + qt * 64)) * DV + w * 64 + (l & 15);
#pragma unroll
    for (int mf = 0; mf < 4; ++mf)
#pragma unroll
        for (int nb = 0; nb < 4; ++nb)
#pragma unroll
            for (int r = 0; r < 4; ++r)
                obase[(size_t)(mf * 16 + (l >> 4) * 4 + r) * DV + nb * 16] = acc[mf][nb][r];
}

// ---------------------------------------------------------------------------
// Reduce: out = sum of nks partials (float4).
// ---------------------------------------------------------------------------
__global__ __launch_bounds__(256) void reduce_kernel(const float* __restrict__ parts,
                                                     float* __restrict__ out,
                                                     int nks) {
    const int n4 = (int)(NOUT / 4);   // 1048576
    int i = blockIdx.x * 256 + threadIdx.x;
    const float4* p = reinterpret_cast<const float4*>(parts);
    float4* o = reinterpret_cast<float4*>(out);
    for (; i < n4; i += 262144) {
        float4 s = p[i];
        for (int j = 1; j < nks; ++j) {
            float4 x = p[i + j * n4];
            s.x += x.x; s.y += x.y; s.z += x.z; s.w += x.w;
        }
        o[i] = s;
    }
}

// ---------------------------------------------------------------------------
extern "C" void kernel_launch(void* const* d_in, const int* in_sizes, int n_in,
                              void* d_out, int out_size, void* d_ws, size_t ws_size,
                              hipStream_t stream) {
    const float* q    = (const float*)d_in[0];
    const float* k    = (const float*)d_in[1];
    const float* v    = (const float*)d_in[2];
    const int*   mask = (const int*)d_in[3];
    const float* w    = (const float*)d_in[4];

    float* out  = (float*)d_out;                       // [B, LQ, DV]
    float* attn = out + NOUT;                          // [B, LQ, LK]
    float* ws   = (float*)d_ws;

    unsigned short* vF = (unsigned short*)(ws + WS_VF16);
    float* part = ws + WS_PART;

    qkw_kernel<<<4096, 256, 0, stream>>>(q, k, w, ws);
    vpack_kernel<<<dim3(64, 4), 256, 0, stream>>>(v, vF);
    rowstat_kernel<<<2048, 256, 0, stream>>>(mask, ws, attn);

    if (ws_size >= WS_NEED(4)) {
        // nks=4: 512 blocks = 2 blocks/CU; bid&3=ks, per-XCD slice locality
        pv_kernel<<<512, 512, 0, stream>>>(attn, vF, part, 4);
        reduce_kernel<<<1024, 256, 0, stream>>>(part, out, 4);
    } else if (ws_size >= WS_NEED(2)) {
        pv_kernel<<<256, 512, 0, stream>>>(attn, vF, part, 2);
        reduce_kernel<<<1024, 256, 0, stream>>>(part, out, 2);
    } else {
        pv_kernel<<<128, 512, 0, stream>>>(attn, vF, out, 1);
    }
}

// Round 11
// 84.224 us; speedup vs baseline: 1.3231x; 1.1076x over previous
//
#include <hip/hip_runtime.h>
#include <math.h>

#define BB 4
#define LQ 2048
#define LK 2048
#define DK 512
#define DV 512

typedef __attribute__((ext_vector_type(8))) _Float16 f16x8;
typedef __attribute__((ext_vector_type(2))) _Float16 f16x2;
typedef __attribute__((ext_vector_type(4))) float f32x4;

// ws layout (f32-element offsets)
#define WS_QW    0                 // f32[8192]
#define WS_KW    8192              // f32[8192]
#define WS_M     16384             // f32[8192]
#define WS_INV   24576             // f32[8192]
#define WS_VF16  32768             // u16 vF[4,194,304] = 8.4 MB
#define NOUT     ((size_t)BB * LQ * DV)

__device__ __forceinline__ unsigned int pk2(float a, float b) {
    auto h = __builtin_amdgcn_cvt_pkrtz(a, b);   // __fp16 ext_vector(2)
    return __builtin_bit_cast(unsigned int, h);
}

// ---------------------------------------------------------------------------
// A: qw/kw — one wave per row.
// ---------------------------------------------------------------------------
__global__ __launch_bounds__(256) void qkw_kernel(const float* __restrict__ q,
                                                  const float* __restrict__ k,
                                                  const float* __restrict__ w,
                                                  float* __restrict__ ws) {
    int gw   = (int)((blockIdx.x * blockDim.x + threadIdx.x) >> 6);
    int lane = threadIdx.x & 63;
    const int nq = BB * LQ;
    const float* row = (gw < nq) ? (q + (size_t)gw * DK) : (k + (size_t)(gw - nq) * DK);

    float acc = 0.f;
#pragma unroll
    for (int j = 0; j < DK; j += 256) {
        int idx = j + lane * 4;
        float4 rv = *reinterpret_cast<const float4*>(row + idx);
        float4 wv = *reinterpret_cast<const float4*>(w + idx);
        acc += rv.x * wv.x + rv.y * wv.y + rv.z * wv.z + rv.w * wv.w;
    }
#pragma unroll
    for (int off = 32; off >= 1; off >>= 1) acc += __shfl_xor(acc, off, 64);
    if (lane == 0) ws[gw] = acc;
}

// ---------------------------------------------------------------------------
// C: v -> MFMA-fragment-ordered fp16 (RTN).
// vF u16 index: (((b*32 + n16)*64 + k32)*64 + lane)*8 + j
//   element = vT[n16*16 + (lane&15)][k32*32 + (lane>>4)*8 + j]
// ---------------------------------------------------------------------------
__global__ __launch_bounds__(256) void vpack_kernel(const float* __restrict__ v,
                                                    unsigned short* __restrict__ vF) {
    __shared__ float tile[32][517];
    const int k32 = blockIdx.x;
    const int b   = blockIdx.y;
    const int k0  = k32 * 32;
    const int t   = threadIdx.x;

#pragma unroll
    for (int i = 0; i < 16; ++i) {
        int flat = i * 256 + t;          // 0..4095
        int row  = flat >> 7;            // 0..31
        int c4   = flat & 127;           // float4 col
        float4 f = *reinterpret_cast<const float4*>(
            v + ((size_t)(b * LK + k0 + row)) * DV + c4 * 4);
        tile[row][c4 * 4 + 0] = f.x;
        tile[row][c4 * 4 + 1] = f.y;
        tile[row][c4 * 4 + 2] = f.z;
        tile[row][c4 * 4 + 3] = f.w;
    }
    __syncthreads();

    const int w = t >> 6, l = t & 63;
    const int rbase = (l >> 4) * 8;
#pragma unroll
    for (int f = 0; f < 8; ++f) {
        int n16 = w * 8 + f;
        int col = n16 * 16 + (l & 15);
        f16x8 vv;
#pragma unroll
        for (int j = 0; j < 8; ++j) vv[j] = (_Float16)tile[rbase + j][col];
        size_t u16base = (((size_t)(b * 32 + n16)) * 64 + k32) * 512;
        *reinterpret_cast<f16x8*>(vF + u16base + l * 8) = vv;
    }
}

// ---------------------------------------------------------------------------
// B1: per-row masked softmax stats + full attn row write.
// ---------------------------------------------------------------------------
__global__ __launch_bounds__(256) void rowstat_kernel(const int* __restrict__ mask,
                                                      float* __restrict__ ws,
                                                      float* __restrict__ attn) {
    __shared__ float kws[LK];
    const int b = (blockIdx.x * 4) / LQ;
    const int t = threadIdx.x;

    const float4* kw4 = reinterpret_cast<const float4*>(ws + WS_KW + b * LK);
#pragma unroll
    for (int i = 0; i < 2; ++i)
        reinterpret_cast<float4*>(kws)[t + i * 256] = kw4[t + i * 256];
    __syncthreads();

    const int wave = t >> 6, lane = t & 63;
    const int rid  = blockIdx.x * 4 + wave;
    const float qwv = ws[WS_QW + rid];
    const int* mrow = mask + (size_t)rid * LK;

    float m = -INFINITY, s = 0.f;
    unsigned int mybits = 0;   // nibble i = mask bits for k = (i*64+lane)*4 ..+3
#pragma unroll
    for (int i = 0; i < 8; ++i) {
        int e = (i * 64 + lane) * 4;
        int4  mi = *reinterpret_cast<const int4*>(mrow + e);
        float4 kv = reinterpret_cast<const float4*>(kws)[i * 64 + lane];
        float vals[4] = {kv.x, kv.y, kv.z, kv.w};
        int   msks[4] = {mi.x, mi.y, mi.z, mi.w};

        unsigned int bits = (msks[0] ? 1u : 0u) | (msks[1] ? 2u : 0u) |
                            (msks[2] ? 4u : 0u) | (msks[3] ? 8u : 0u);
        mybits |= bits << (i * 4);

#pragma unroll
        for (int j = 0; j < 4; ++j) {
            float sc = qwv - vals[j];
            sc = fmaxf(sc, 0.01f * sc);
            if (msks[j]) {
                if (sc > m) { s = s * __expf(m - sc) + 1.f; m = sc; }
                else        { s += __expf(sc - m); }
            }
        }
    }
#pragma unroll
    for (int off = 32; off >= 1; off >>= 1) {
        float mo = __shfl_xor(m, off, 64);
        float so = __shfl_xor(s, off, 64);
        float M  = fmaxf(m, mo);
        float sa = (m  == M) ? s  : s  * __expf(m  - M);
        float sb = (mo == M) ? so : so * __expf(mo - M);
        m = M; s = sa + sb;
    }
    const float inv = (s > 0.f) ? 1.f / s : 0.f;
    if (lane == 0) {
        ws[WS_M   + rid] = m;
        ws[WS_INV + rid] = inv;
    }

    // ---- pass 2: exact p, coalesced attn write ----
    float* arow = attn + (size_t)rid * LK;
#pragma unroll
    for (int i = 0; i < 8; ++i) {
        float4 kv = reinterpret_cast<const float4*>(kws)[i * 64 + lane];
        float vals[4] = {kv.x, kv.y, kv.z, kv.w};
        unsigned int bits = (mybits >> (i * 4)) & 0xFu;
        float p[4];
#pragma unroll
        for (int j = 0; j < 4; ++j) {
            float sc = qwv - vals[j];
            sc = fmaxf(sc, 0.01f * sc);
            p[j] = (bits & (1u << j)) ? __expf(sc - m) * inv : 0.f;
        }
        *reinterpret_cast<float4*>(arow + (i * 64 + lane) * 4) =
            make_float4(p[0], p[1], p[2], p[3]);
    }
}

// ---------------------------------------------------------------------------
// B2: PV matmul, fp16 two-term (p = h16 + r16; v = v16 RTN), N-SPLIT.
// Block = 64 q-rows x 128 n-cols x full K. 256 thr (4 waves); wave owns 2 nb.
// No partials, no reduce: direct out write. 512 blocks = 2/CU.
// bid = qt*16 + b*4 + ns  ->  XCD = (b*4+ns)&7: one 512KB vF slice per XCD.
// ---------------------------------------------------------------------------
__global__ __launch_bounds__(256, 2) void pv_kernel(
        const float* __restrict__ attn,
        const unsigned short* __restrict__ vF,
        float* __restrict__ out) {
    __shared__ unsigned int pH32[2][1024];   // hi fp16 pairs   (8 KB)
    __shared__ unsigned int pL32[2][1024];   // residual pairs  (8 KB)

    const int bid = blockIdx.x;
    const int ns  = bid & 3;
    const int b   = (bid >> 2) & 3;
    const int qt  = bid >> 4;              // 0..31
    const int ksteps = LK >> 5;            // 64

    const int t = threadIdx.x;
    const int w = t >> 6, l = t & 63;

    // A staging decode: thread t -> (mf = t>>6, l_a = t&63), writes u32[4t..4t+4)
    // element: row = (t>>6)*16 + (t&15), k in [kb, kb+8), kb = ((t>>4)&3)*8
    const int row_a = (t >> 6) * 16 + (t & 15);
    const int kb    = ((t >> 4) & 3) * 8;
    const int rid   = b * LQ + qt * 64 + row_a;
    const float* arow = attn + (size_t)rid * LK + kb;

    // B: wave w owns n16 = ns*8 + w*2 + nb, nb in {0,1}
    const unsigned short* bsrc[2];
#pragma unroll
    for (int nb = 0; nb < 2; ++nb)
        bsrc[nb] = vF + (((size_t)(b * 32 + ns * 8 + w * 2 + nb)) * 64) * 512
                      + (size_t)l * 8;

    // helper: stage 8 floats (2 float4) into H/L u32[4]
    auto stage = [&](const float4& x, const float4& y, int buf) {
        unsigned int H[4], L[4];
        float f[8] = {x.x, x.y, x.z, x.w, y.x, y.y, y.z, y.w};
#pragma unroll
        for (int jw = 0; jw < 4; ++jw) {
            unsigned int h01 = pk2(f[2 * jw], f[2 * jw + 1]);
            f16x2 hv = __builtin_bit_cast(f16x2, h01);
            H[jw] = h01;
            L[jw] = pk2(f[2 * jw] - (float)hv[0], f[2 * jw + 1] - (float)hv[1]);
        }
        *reinterpret_cast<uint4*>(&pH32[buf][t * 4]) = *reinterpret_cast<uint4*>(H);
        *reinterpret_cast<uint4*>(&pL32[buf][t * 4]) = *reinterpret_cast<uint4*>(L);
    };

    // prologue: B(0) in regs; A(0) staged to buf0; A(1) in regs
    f16x8 bC[2], bN[2];
#pragma unroll
    for (int nb = 0; nb < 2; ++nb)
        bC[nb] = *reinterpret_cast<const f16x8*>(bsrc[nb]);

    {
        float4 x = *reinterpret_cast<const float4*>(arow);
        float4 y = *reinterpret_cast<const float4*>(arow + 4);
        stage(x, y, 0);
    }
    float4 aCx = *reinterpret_cast<const float4*>(arow + 32);
    float4 aCy = *reinterpret_cast<const float4*>(arow + 36);

    f32x4 acc[4][2];
#pragma unroll
    for (int mf = 0; mf < 4; ++mf)
#pragma unroll
        for (int nb = 0; nb < 2; ++nb)
            acc[mf][nb] = (f32x4){0.f, 0.f, 0.f, 0.f};

    __syncthreads();

    for (int s = 0; s < ksteps; ++s) {
        const int buf  = s & 1;
        const int nbuf = buf ^ 1;
        const int sn   = (s + 1 < ksteps) ? s + 1 : s;   // B prefetch step
        const int sn2  = (s + 2 < ksteps) ? s + 2 : s;   // A prefetch step

        // 1. global prefetches
#pragma unroll
        for (int nb = 0; nb < 2; ++nb)
            bN[nb] = *reinterpret_cast<const f16x8*>(bsrc[nb] + (size_t)sn * 512);
        float4 aNx = *reinterpret_cast<const float4*>(arow + sn2 * 32);
        float4 aNy = *reinterpret_cast<const float4*>(arow + sn2 * 32 + 4);

        // 2. stage A(s+1) (regs from last iter) into nbuf
        stage(aCx, aCy, nbuf);

        // 3. ds_read this step's A fragments from buf
        const f16x8* pHf = reinterpret_cast<const f16x8*>(pH32[buf]);
        const f16x8* pLf = reinterpret_cast<const f16x8*>(pL32[buf]);
        f16x8 aH[4], aL[4];
#pragma unroll
        for (int mf = 0; mf < 4; ++mf) {
            aH[mf] = pHf[mf * 64 + l];
            aL[mf] = pLf[mf * 64 + l];
        }

        // 4. MFMA cluster (16)
        __builtin_amdgcn_s_setprio(1);
#pragma unroll
        for (int nb = 0; nb < 2; ++nb)
#pragma unroll
            for (int mf = 0; mf < 4; ++mf) {
                acc[mf][nb] = __builtin_amdgcn_mfma_f32_16x16x32_f16(aH[mf], bC[nb], acc[mf][nb], 0, 0, 0);
                acc[mf][nb] = __builtin_amdgcn_mfma_f32_16x16x32_f16(aL[mf], bC[nb], acc[mf][nb], 0, 0, 0);
            }
        __builtin_amdgcn_s_setprio(0);

        __syncthreads();   // single barrier per step

#pragma unroll
        for (int nb = 0; nb < 2; ++nb) bC[nb] = bN[nb];
        aCx = aNx; aCy = aNy;
    }

    // ---- epilogue: direct out write. col = ns*128 + (w*2+nb)*16 + (l&15),
    //      row = qt*64 + mf*16 + (l>>4)*4 + r ----
    float* obase = out + ((size_t)(b * LQ + qt * 64)) * DV
                       + ns * 128 + w * 32 + (l & 15);
#pragma unroll
    for (int mf = 0; mf < 4; ++mf)
#pragma unroll
        for (int nb = 0; nb < 2; ++nb)
#pragma unroll
            for (int r = 0; r < 4; ++r)
                obase[(size_t)(mf * 16 + (l >> 4) * 4 + r) * DV + nb * 16] = acc[mf][nb][r];
}

// ---------------------------------------------------------------------------
extern "C" void kernel_launch(void* const* d_in, const int* in_sizes, int n_in,
                              void* d_out, int out_size, void* d_ws, size_t ws_size,
                              hipStream_t stream) {
    const float* q    = (const float*)d_in[0];
    const float* k    = (const float*)d_in[1];
    const float* v    = (const float*)d_in[2];
    const int*   mask = (const int*)d_in[3];
    const float* w    = (const float*)d_in[4];

    float* out  = (float*)d_out;                       // [B, LQ, DV]
    float* attn = out + NOUT;                          // [B, LQ, LK]
    float* ws   = (float*)d_ws;

    unsigned short* vF = (unsigned short*)(ws + WS_VF16);

    qkw_kernel<<<4096, 256, 0, stream>>>(q, k, w, ws);
    vpack_kernel<<<dim3(64, 4), 256, 0, stream>>>(v, vF);
    rowstat_kernel<<<2048, 256, 0, stream>>>(mask, ws, attn);
    pv_kernel<<<512, 256, 0, stream>>>(attn, vF, out);
}

// Round 12
// 81.255 us; speedup vs baseline: 1.3714x; 1.0365x over previous
//
#include <hip/hip_runtime.h>
#include <math.h>

#define BB 4
#define LQ 2048
#define LK 2048
#define DK 512
#define DV 512

typedef __attribute__((ext_vector_type(8))) _Float16 f16x8;
typedef __attribute__((ext_vector_type(2))) _Float16 f16x2;
typedef __attribute__((ext_vector_type(4))) float f32x4;

// ws layout (f32-element offsets)
#define WS_QW    0                 // f32[8192]
#define WS_KW    8192              // f32[8192]
#define WS_M     16384             // f32[8192]
#define WS_INV   24576             // f32[8192]
#define WS_VF16  32768             // u16 vF[4,194,304] = 8.4 MB
#define NOUT     ((size_t)BB * LQ * DV)

__device__ __forceinline__ unsigned int pk2(float a, float b) {
    auto h = __builtin_amdgcn_cvt_pkrtz(a, b);   // __fp16 ext_vector(2)
    return __builtin_bit_cast(unsigned int, h);
}

// ---------------------------------------------------------------------------
// A: qw/kw — one wave per row.
// ---------------------------------------------------------------------------
__global__ __launch_bounds__(256) void qkw_kernel(const float* __restrict__ q,
                                                  const float* __restrict__ k,
                                                  const float* __restrict__ w,
                                                  float* __restrict__ ws) {
    int gw   = (int)((blockIdx.x * blockDim.x + threadIdx.x) >> 6);
    int lane = threadIdx.x & 63;
    const int nq = BB * LQ;
    const float* row = (gw < nq) ? (q + (size_t)gw * DK) : (k + (size_t)(gw - nq) * DK);

    float acc = 0.f;
#pragma unroll
    for (int j = 0; j < DK; j += 256) {
        int idx = j + lane * 4;
        float4 rv = *reinterpret_cast<const float4*>(row + idx);
        float4 wv = *reinterpret_cast<const float4*>(w + idx);
        acc += rv.x * wv.x + rv.y * wv.y + rv.z * wv.z + rv.w * wv.w;
    }
#pragma unroll
    for (int off = 32; off >= 1; off >>= 1) acc += __shfl_xor(acc, off, 64);
    if (lane == 0) ws[gw] = acc;
}

// ---------------------------------------------------------------------------
// C: v -> MFMA-fragment-ordered fp16 (RTN).
// vF u16 index: (((b*32 + n16)*64 + k32)*64 + lane)*8 + j
//   element = vT[n16*16 + (lane&15)][k32*32 + (lane>>4)*8 + j]
// ---------------------------------------------------------------------------
__global__ __launch_bounds__(256) void vpack_kernel(const float* __restrict__ v,
                                                    unsigned short* __restrict__ vF) {
    __shared__ float tile[32][517];
    const int k32 = blockIdx.x;
    const int b   = blockIdx.y;
    const int k0  = k32 * 32;
    const int t   = threadIdx.x;

#pragma unroll
    for (int i = 0; i < 16; ++i) {
        int flat = i * 256 + t;          // 0..4095
        int row  = flat >> 7;            // 0..31
        int c4   = flat & 127;           // float4 col
        float4 f = *reinterpret_cast<const float4*>(
            v + ((size_t)(b * LK + k0 + row)) * DV + c4 * 4);
        tile[row][c4 * 4 + 0] = f.x;
        tile[row][c4 * 4 + 1] = f.y;
        tile[row][c4 * 4 + 2] = f.z;
        tile[row][c4 * 4 + 3] = f.w;
    }
    __syncthreads();

    const int w = t >> 6, l = t & 63;
    const int rbase = (l >> 4) * 8;
#pragma unroll
    for (int f = 0; f < 8; ++f) {
        int n16 = w * 8 + f;
        int col = n16 * 16 + (l & 15);
        f16x8 vv;
#pragma unroll
        for (int j = 0; j < 8; ++j) vv[j] = (_Float16)tile[rbase + j][col];
        size_t u16base = (((size_t)(b * 32 + n16)) * 64 + k32) * 512;
        *reinterpret_cast<f16x8*>(vF + u16base + l * 8) = vv;
    }
}

// ---------------------------------------------------------------------------
// B1: per-row masked softmax stats + full attn row write.
// ---------------------------------------------------------------------------
__global__ __launch_bounds__(256) void rowstat_kernel(const int* __restrict__ mask,
                                                      float* __restrict__ ws,
                                                      float* __restrict__ attn) {
    __shared__ float kws[LK];
    const int b = (blockIdx.x * 4) / LQ;
    const int t = threadIdx.x;

    const float4* kw4 = reinterpret_cast<const float4*>(ws + WS_KW + b * LK);
#pragma unroll
    for (int i = 0; i < 2; ++i)
        reinterpret_cast<float4*>(kws)[t + i * 256] = kw4[t + i * 256];
    __syncthreads();

    const int wave = t >> 6, lane = t & 63;
    const int rid  = blockIdx.x * 4 + wave;
    const float qwv = ws[WS_QW + rid];
    const int* mrow = mask + (size_t)rid * LK;

    float m = -INFINITY, s = 0.f;
    unsigned int mybits = 0;   // nibble i = mask bits for k = (i*64+lane)*4 ..+3
#pragma unroll
    for (int i = 0; i < 8; ++i) {
        int e = (i * 64 + lane) * 4;
        int4  mi = *reinterpret_cast<const int4*>(mrow + e);
        float4 kv = reinterpret_cast<const float4*>(kws)[i * 64 + lane];
        float vals[4] = {kv.x, kv.y, kv.z, kv.w};
        int   msks[4] = {mi.x, mi.y, mi.z, mi.w};

        unsigned int bits = (msks[0] ? 1u : 0u) | (msks[1] ? 2u : 0u) |
                            (msks[2] ? 4u : 0u) | (msks[3] ? 8u : 0u);
        mybits |= bits << (i * 4);

#pragma unroll
        for (int j = 0; j < 4; ++j) {
            float sc = qwv - vals[j];
            sc = fmaxf(sc, 0.01f * sc);
            if (msks[j]) {
                if (sc > m) { s = s * __expf(m - sc) + 1.f; m = sc; }
                else        { s += __expf(sc - m); }
            }
        }
    }
#pragma unroll
    for (int off = 32; off >= 1; off >>= 1) {
        float mo = __shfl_xor(m, off, 64);
        float so = __shfl_xor(s, off, 64);
        float M  = fmaxf(m, mo);
        float sa = (m  == M) ? s  : s  * __expf(m  - M);
        float sb = (mo == M) ? so : so * __expf(mo - M);
        m = M; s = sa + sb;
    }
    const float inv = (s > 0.f) ? 1.f / s : 0.f;
    if (lane == 0) {
        ws[WS_M   + rid] = m;
        ws[WS_INV + rid] = inv;
    }

    // ---- pass 2: exact p, coalesced attn write ----
    float* arow = attn + (size_t)rid * LK;
#pragma unroll
    for (int i = 0; i < 8; ++i) {
        float4 kv = reinterpret_cast<const float4*>(kws)[i * 64 + lane];
        float vals[4] = {kv.x, kv.y, kv.z, kv.w};
        unsigned int bits = (mybits >> (i * 4)) & 0xFu;
        float p[4];
#pragma unroll
        for (int j = 0; j < 4; ++j) {
            float sc = qwv - vals[j];
            sc = fmaxf(sc, 0.01f * sc);
            p[j] = (bits & (1u << j)) ? __expf(sc - m) * inv : 0.f;
        }
        *reinterpret_cast<float4*>(arow + (i * 64 + lane) * 4) =
            make_float4(p[0], p[1], p[2], p[3]);
    }
}

// ---------------------------------------------------------------------------
// B2: PV matmul, fp16 two-term (p = h16 + r16; v = v16 RTN), N-SPLIT.
// Block = 64 q-rows x 128 n-cols x full K. 256 thr (4 waves); wave owns 2 nb.
// XCD-COLOCATED decode: bid = xcd + 8*(g*4 + ns), xcd = (qt*4+b)&7,
// g = (qt*4+b)>>3. All 4 ns-blocks of a (b,qt) share one XCD -> attn step
// window L2-resident (read HBM once); each XCD's 2MB vF slice L2-resident.
// ---------------------------------------------------------------------------
__global__ __launch_bounds__(256, 2) void pv_kernel(
        const float* __restrict__ attn,
        const unsigned short* __restrict__ vF,
        float* __restrict__ out) {
    __shared__ unsigned int pH32[2][1024];   // hi fp16 pairs   (8 KB)
    __shared__ unsigned int pL32[2][1024];   // residual pairs  (8 KB)

    const int bid  = blockIdx.x;
    const int xcd  = bid & 7;
    const int rest = bid >> 3;             // 0..63
    const int g    = rest >> 2;            // 0..15
    const int ns   = rest & 3;
    const int qt4b = g * 8 + xcd;          // qt*4 + b, 0..127
    const int b    = qt4b & 3;
    const int qt   = qt4b >> 2;            // 0..31
    const int ksteps = LK >> 5;            // 64

    const int t = threadIdx.x;
    const int w = t >> 6, l = t & 63;

    // A staging decode: thread t -> writes u32[4t..4t+4)
    // element: row = (t>>6)*16 + (t&15), k in [kb, kb+8), kb = ((t>>4)&3)*8
    const int row_a = (t >> 6) * 16 + (t & 15);
    const int kb    = ((t >> 4) & 3) * 8;
    const int rid   = b * LQ + qt * 64 + row_a;
    const float* arow = attn + (size_t)rid * LK + kb;

    // B: wave w owns n16 = ns*8 + w*2 + nb, nb in {0,1}
    const unsigned short* bsrc[2];
#pragma unroll
    for (int nb = 0; nb < 2; ++nb)
        bsrc[nb] = vF + (((size_t)(b * 32 + ns * 8 + w * 2 + nb)) * 64) * 512
                      + (size_t)l * 8;

    // helper: stage 8 floats (2 float4) into H/L u32[4]
    auto stage = [&](const float4& x, const float4& y, int buf) {
        unsigned int H[4], L[4];
        float f[8] = {x.x, x.y, x.z, x.w, y.x, y.y, y.z, y.w};
#pragma unroll
        for (int jw = 0; jw < 4; ++jw) {
            unsigned int h01 = pk2(f[2 * jw], f[2 * jw + 1]);
            f16x2 hv = __builtin_bit_cast(f16x2, h01);
            H[jw] = h01;
            L[jw] = pk2(f[2 * jw] - (float)hv[0], f[2 * jw + 1] - (float)hv[1]);
        }
        *reinterpret_cast<uint4*>(&pH32[buf][t * 4]) = *reinterpret_cast<uint4*>(H);
        *reinterpret_cast<uint4*>(&pL32[buf][t * 4]) = *reinterpret_cast<uint4*>(L);
    };

    // prologue: B(0) in regs; A(0) staged to buf0; A(1) in regs
    f16x8 bC[2], bN[2];
#pragma unroll
    for (int nb = 0; nb < 2; ++nb)
        bC[nb] = *reinterpret_cast<const f16x8*>(bsrc[nb]);

    {
        float4 x = *reinterpret_cast<const float4*>(arow);
        float4 y = *reinterpret_cast<const float4*>(arow + 4);
        stage(x, y, 0);
    }
    float4 aCx = *reinterpret_cast<const float4*>(arow + 32);
    float4 aCy = *reinterpret_cast<const float4*>(arow + 36);

    f32x4 acc[4][2];
#pragma unroll
    for (int mf = 0; mf < 4; ++mf)
#pragma unroll
        for (int nb = 0; nb < 2; ++nb)
            acc[mf][nb] = (f32x4){0.f, 0.f, 0.f, 0.f};

    __syncthreads();

    for (int s = 0; s < ksteps; ++s) {
        const int buf  = s & 1;
        const int nbuf = buf ^ 1;
        const int sn   = (s + 1 < ksteps) ? s + 1 : s;   // B prefetch step
        const int sn2  = (s + 2 < ksteps) ? s + 2 : s;   // A prefetch step

        // 1. global prefetches
#pragma unroll
        for (int nb = 0; nb < 2; ++nb)
            bN[nb] = *reinterpret_cast<const f16x8*>(bsrc[nb] + (size_t)sn * 512);
        float4 aNx = *reinterpret_cast<const float4*>(arow + sn2 * 32);
        float4 aNy = *reinterpret_cast<const float4*>(arow + sn2 * 32 + 4);

        // 2. stage A(s+1) (regs from last iter) into nbuf
        stage(aCx, aCy, nbuf);

        // 3. ds_read this step's A fragments from buf
        const f16x8* pHf = reinterpret_cast<const f16x8*>(pH32[buf]);
        const f16x8* pLf = reinterpret_cast<const f16x8*>(pL32[buf]);
        f16x8 aH[4], aL[4];
#pragma unroll
        for (int mf = 0; mf < 4; ++mf) {
            aH[mf] = pHf[mf * 64 + l];
            aL[mf] = pLf[mf * 64 + l];
        }

        // 4. MFMA cluster (16)
        __builtin_amdgcn_s_setprio(1);
#pragma unroll
        for (int nb = 0; nb < 2; ++nb)
#pragma unroll
            for (int mf = 0; mf < 4; ++mf) {
                acc[mf][nb] = __builtin_amdgcn_mfma_f32_16x16x32_f16(aH[mf], bC[nb], acc[mf][nb], 0, 0, 0);
                acc[mf][nb] = __builtin_amdgcn_mfma_f32_16x16x32_f16(aL[mf], bC[nb], acc[mf][nb], 0, 0, 0);
            }
        __builtin_amdgcn_s_setprio(0);

        __syncthreads();   // single barrier per step

#pragma unroll
        for (int nb = 0; nb < 2; ++nb) bC[nb] = bN[nb];
        aCx = aNx; aCy = aNy;
    }

    // ---- epilogue: direct out write. col = ns*128 + (w*2+nb)*16 + (l&15),
    //      row = qt*64 + mf*16 + (l>>4)*4 + r ----
    float* obase = out + ((size_t)(b * LQ + qt * 64)) * DV
                       + ns * 128 + w * 32 + (l & 15);
#pragma unroll
    for (int mf = 0; mf < 4; ++mf)
#pragma unroll
        for (int nb = 0; nb < 2; ++nb)
#pragma unroll
            for (int r = 0; r < 4; ++r)
                obase[(size_t)(mf * 16 + (l >> 4) * 4 + r) * DV + nb * 16] = acc[mf][nb][r];
}

// ---------------------------------------------------------------------------
extern "C" void kernel_launch(void* const* d_in, const int* in_sizes, int n_in,
                              void* d_out, int out_size, void* d_ws, size_t ws_size,
                              hipStream_t stream) {
    const float* q    = (const float*)d_in[0];
    const float* k    = (const float*)d_in[1];
    const float* v    = (const float*)d_in[2];
    const int*   mask = (const int*)d_in[3];
    const float* w    = (const float*)d_in[4];

    float* out  = (float*)d_out;                       // [B, LQ, DV]
    float* attn = out + NOUT;                          // [B, LQ, LK]
    float* ws   = (float*)d_ws;

    unsigned short* vF = (unsigned short*)(ws + WS_VF16);

    qkw_kernel<<<4096, 256, 0, stream>>>(q, k, w, ws);
    vpack_kernel<<<dim3(64, 4), 256, 0, stream>>>(v, vF);
    rowstat_kernel<<<2048, 256, 0, stream>>>(mask, ws, attn);
    pv_kernel<<<512, 256, 0, stream>>>(attn, vF, out);
}